// Round 1
// baseline (3587.040 us; speedup 1.0000x reference)
//
#include <hip/hip_runtime.h>

typedef unsigned int u32;
typedef unsigned short u16;
typedef __bf16 bf16x8 __attribute__((ext_vector_type(8)));
typedef float f32x16 __attribute__((ext_vector_type(16)));
typedef float f32x4v __attribute__((ext_vector_type(4)));
typedef u32 u32x4 __attribute__((ext_vector_type(4)));
typedef u32 u32x2 __attribute__((ext_vector_type(2)));

#define BATCH    32768
#define DIN      256
#define UNITS    512
#define BM       64
#define NTHREADS 512
#define NSTEP    6
#define DT       (1.0f/6.0f)
#define SMEM_BYTES (65536 + 65536 + 2048 + 2048)

__device__ __forceinline__ u16 f2bf(float f) {
  u32 u = __builtin_bit_cast(u32, f);
  u32 r = u + 0x7fffu + ((u >> 16) & 1u);   // RNE
  return (u16)(r >> 16);
}
__device__ __forceinline__ float bf2f(u16 b) {
  return __builtin_bit_cast(float, (u32)b << 16);
}
__device__ __forceinline__ float fast_tanh(float x) {
  // tanh(x) = (e^{2x}-1)/(e^{2x}+1), e^{2x} = 2^{x*2*log2(e)}
  float t = fminf(fmaxf(x * 2.885390082f, -60.f), 60.f);
  float a = __builtin_amdgcn_exp2f(t);
  return (a - 1.f) * __builtin_amdgcn_rcpf(a + 1.f);
}

// Pack K (256x512) and R (512x512) f32 row-major into bf16 B-fragment order:
// Rp chunk c = g*512 + n (g = kb*2+hi) holds rows g*8..g*8+7, col n (16B per lane).
__global__ void pack_weights(const float* __restrict__ Km, const float* __restrict__ Rm,
                             u16* __restrict__ Kp, u16* __restrict__ Rp) {
  int c = blockIdx.x * 256 + threadIdx.x;          // 0 .. 49151
  if (c < 32768) {
    int n = c & 511, g = c >> 9;                   // g < 64
    u32x4 p;
#pragma unroll
    for (int i = 0; i < 4; ++i) {
      u16 lo = f2bf(Rm[(g * 8 + 2 * i) * 512 + n]);
      u16 hh = f2bf(Rm[(g * 8 + 2 * i + 1) * 512 + n]);
      p[i] = (u32)lo | ((u32)hh << 16);
    }
    ((u32x4*)Rp)[c] = p;
  } else {
    int c2 = c - 32768;                            // < 16384
    int n = c2 & 511, g = c2 >> 9;                 // g < 32
    u32x4 p;
#pragma unroll
    for (int i = 0; i < 4; ++i) {
      u16 lo = f2bf(Km[(g * 8 + 2 * i) * 512 + n]);
      u16 hh = f2bf(Km[(g * 8 + 2 * i + 1) * 512 + n]);
      p[i] = (u32)lo | ((u32)hh << 16);
    }
    ((u32x4*)Kp)[c2] = p;
  }
}

__global__ __launch_bounds__(NTHREADS, 2)
void ctrnn_fused(const float* __restrict__ X, const float* __restrict__ H0,
                 const u16* __restrict__ Kp, const u16* __restrict__ Rp,
                 const float* __restrict__ bias, const float* __restrict__ scale,
                 float* __restrict__ out) {
  extern __shared__ char smem[];
  char* heL  = smem;                     // 64KB: he [64][512] bf16, swizzled (also x-stage in prologue)
  char* xkbL = smem + 65536;             // 64KB: xkb bf16 in C-fragment order [wave][nt][lane][16]
  float* biasL  = (float*)(smem + 131072);
  float* scaleL = (float*)(smem + 131072 + 2048);

  const int tid  = threadIdx.x;
  const int lane = tid & 63;
  const int wv   = tid >> 6;             // 0..7
  const int wm   = wv >> 2, wn = wv & 3; // 2 x 4 wave grid
  const int ln   = lane & 31, hi = lane >> 5;
  const long r0  = (long)blockIdx.x * BM;

  biasL[tid]  = bias[tid];
  scaleL[tid] = scale[tid];

  // stage x tile -> bf16 LDS [64][256], rows 512B, swizzle ^((m&7)<<4)
  {
    const f32x4v* X4 = (const f32x4v*)(X + r0 * DIN);
#pragma unroll
    for (int i = 0; i < 8; ++i) {
      int flat = i * NTHREADS + tid;     // 0..4095 float4-chunks
      int m = flat >> 6, c4 = flat & 63;
      f32x4v v = X4[m * 64 + c4];
      u32x2 p;
      p.x = (u32)f2bf(v.x) | ((u32)f2bf(v.y) << 16);
      p.y = (u32)f2bf(v.z) | ((u32)f2bf(v.w) << 16);
      *(u32x2*)(heL + m * 512 + ((c4 * 8) ^ ((m & 7) << 4))) = p;
    }
  }
  __syncthreads();

  const int jc  = wn * 128 + ln;         // wave col base (+ nt*32)
  const int jc2 = jc * 2;
  float scl[4];
#pragma unroll
  for (int nt = 0; nt < 4; ++nt) scl[nt] = scaleL[jc + nt * 32];

  const int mA  = wm * 32 + ln;          // A-fragment row
  const int swA = (ln & 7) << 4;

  // ---- prologue: xkb = x @ K + bias (MFMA over DIN=256, 16 k-blocks) ----
  {
    f32x16 pre[4];
#pragma unroll
    for (int nt = 0; nt < 4; ++nt) {
      float b = biasL[jc + nt * 32];
#pragma unroll
      for (int r = 0; r < 16; ++r) pre[nt][r] = b;
    }
    const u32x4* Kp4 = (const u32x4*)Kp;
#pragma unroll 2
    for (int kb = 0; kb < 16; ++kb) {
      bf16x8 a = __builtin_bit_cast(bf16x8,
          *(const u32x4*)(heL + mA * 512 + (((kb * 32) | (hi * 16)) ^ swA)));
#pragma unroll
      for (int nt = 0; nt < 4; ++nt) {
        bf16x8 b = __builtin_bit_cast(bf16x8, Kp4[(kb * 2 + hi) * 512 + jc + nt * 32]);
        pre[nt] = __builtin_amdgcn_mfma_f32_32x32x16_bf16(a, b, pre[nt], 0, 0, 0);
      }
    }
#pragma unroll
    for (int nt = 0; nt < 4; ++nt) {
      u32 pw[8];
#pragma unroll
      for (int i = 0; i < 8; ++i)
        pw[i] = (u32)f2bf(pre[nt][2 * i]) | ((u32)f2bf(pre[nt][2 * i + 1]) << 16);
      int base = ((wv * 4 + nt) * 64 + lane) * 32;
      u32x4 p0 = {pw[0], pw[1], pw[2], pw[3]};
      u32x4 p1 = {pw[4], pw[5], pw[6], pw[7]};
      *(u32x4*)(xkbL + base)      = p0;
      *(u32x4*)(xkbL + base + 16) = p1;
    }
  }

  // load h (f32) in C-fragment layout
  float h[4][16], acc[4][16];
  const int mbase = wm * 32 + hi * 4;
#pragma unroll
  for (int nt = 0; nt < 4; ++nt)
#pragma unroll
    for (int r = 0; r < 16; ++r) {
      int m = mbase + (r & 3) + ((r >> 2) << 3);
      h[nt][r] = H0[(r0 + m) * UNITS + jc + nt * 32];
    }

  __syncthreads();   // all x-stage reads done; heL now the he buffer

  // write he_1 = h
#pragma unroll
  for (int nt = 0; nt < 4; ++nt)
#pragma unroll
    for (int r = 0; r < 16; ++r) {
      int m = mbase + (r & 3) + ((r >> 2) << 3);
      *(u16*)(heL + m * 1024 + ((jc2 + nt * 64) ^ ((m & 7) << 4))) = f2bf(h[nt][r]);
    }
  __syncthreads();

  const u32x4* Rp4 = (const u32x4*)Rp;

  for (int step = 0; step < NSTEP; ++step) {
    for (int ev = 0; ev < 4; ++ev) {
      // pre = xkb (re-init from LDS, own-thread data)
      f32x16 pre[4];
#pragma unroll
      for (int nt = 0; nt < 4; ++nt) {
        int base = ((wv * 4 + nt) * 64 + lane) * 32;
        u32x4 q0 = *(const u32x4*)(xkbL + base);
        u32x4 q1 = *(const u32x4*)(xkbL + base + 16);
#pragma unroll
        for (int i = 0; i < 4; ++i) {
          pre[nt][2 * i]         = bf2f((u16)(q0[i] & 0xffffu));
          pre[nt][2 * i + 1]     = bf2f((u16)(q0[i] >> 16));
          pre[nt][8 + 2 * i]     = bf2f((u16)(q1[i] & 0xffffu));
          pre[nt][8 + 2 * i + 1] = bf2f((u16)(q1[i] >> 16));
        }
      }
      // pre += he @ R  (32 k-blocks, B-frags streamed from L2)
#pragma unroll 2
      for (int kb = 0; kb < 32; ++kb) {
        bf16x8 a = __builtin_bit_cast(bf16x8,
            *(const u32x4*)(heL + mA * 1024 + (((kb * 32) | (hi * 16)) ^ swA)));
#pragma unroll
        for (int nt = 0; nt < 4; ++nt) {
          bf16x8 b = __builtin_bit_cast(bf16x8, Rp4[(kb * 2 + hi) * 512 + jc + nt * 32]);
          pre[nt] = __builtin_amdgcn_mfma_f32_32x32x16_bf16(a, b, pre[nt], 0, 0, 0);
        }
      }

      // epilogue: k = scale*tanh(pre) - he ; RK4 bookkeeping
      const float wk = (ev == 1 || ev == 2) ? 2.f : 1.f;
      const float ce = (ev < 2) ? (DT * 0.5f) : ((ev == 2) ? DT : 0.f);
      u32 hpk[4][8];
#pragma unroll
      for (int nt = 0; nt < 4; ++nt) {
#pragma unroll
        for (int rp = 0; rp < 8; ++rp) {
          u16 nb[2];
#pragma unroll
          for (int half = 0; half < 2; ++half) {
            int r = rp * 2 + half;
            int m = mbase + (r & 3) + ((r >> 2) << 3);
            int byte = m * 1024 + ((jc2 + nt * 64) ^ ((m & 7) << 4));
            float u = scl[nt] * fast_tanh(pre[nt][r]);
            float hev = (ev == 0) ? h[nt][r] : bf2f(*(const u16*)(heL + byte));
            float k = u - hev;
            float ac = (ev == 0 ? 0.f : acc[nt][r]) + wk * k;
            acc[nt][r] = ac;
            if (ev == 3) h[nt][r] += (DT / 6.f) * ac;
            nb[half] = f2bf(h[nt][r] + ce * k);   // he_next (ev==3: ce=0 -> updated h)
          }
          hpk[nt][rp] = (u32)nb[0] | ((u32)nb[1] << 16);
        }
      }
      __syncthreads();   // all MFMA/readback reads of heL complete
      if (!(step == NSTEP - 1 && ev == 3)) {
#pragma unroll
        for (int nt = 0; nt < 4; ++nt)
#pragma unroll
          for (int rp = 0; rp < 8; ++rp)
#pragma unroll
            for (int half = 0; half < 2; ++half) {
              int r = rp * 2 + half;
              int m = mbase + (r & 3) + ((r >> 2) << 3);
              int byte = m * 1024 + ((jc2 + nt * 64) ^ ((m & 7) << 4));
              *(u16*)(heL + byte) = (u16)(half ? (hpk[nt][rp] >> 16) : (hpk[nt][rp] & 0xffffu));
            }
      }
      __syncthreads();   // he_{i+1} visible
    }
  }

  // store final h
#pragma unroll
  for (int nt = 0; nt < 4; ++nt)
#pragma unroll
    for (int r = 0; r < 16; ++r) {
      int m = mbase + (r & 3) + ((r >> 2) << 3);
      out[(r0 + m) * UNITS + jc + nt * 32] = h[nt][r];
    }
}

extern "C" void kernel_launch(void* const* d_in, const int* in_sizes, int n_in,
                              void* d_out, int out_size, void* d_ws, size_t ws_size,
                              hipStream_t stream) {
  const float* X     = (const float*)d_in[0];
  const float* H0    = (const float*)d_in[1];
  const float* Km    = (const float*)d_in[2];
  const float* Rm    = (const float*)d_in[3];
  const float* bias  = (const float*)d_in[4];
  const float* scale = (const float*)d_in[5];
  float* out = (float*)d_out;

  u16* Rp = (u16*)d_ws;                  // 512*512 bf16 = 512KB
  u16* Kp = Rp + UNITS * UNITS;          // 256*512 bf16 = 256KB

  (void)hipFuncSetAttribute((const void*)ctrnn_fused,
                            hipFuncAttributeMaxDynamicSharedMemorySize, SMEM_BYTES);

  pack_weights<<<192, 256, 0, stream>>>(Km, Rm, Kp, Rp);
  ctrnn_fused<<<BATCH / BM, NTHREADS, SMEM_BYTES, stream>>>(X, H0, Kp, Rp, bias, scale, out);
}

// Round 2
// 1016.883 us; speedup vs baseline: 3.5275x; 3.5275x over previous
//
#include <hip/hip_runtime.h>

typedef unsigned int u32;
typedef unsigned short u16;
typedef __bf16 bf16x8 __attribute__((ext_vector_type(8)));
typedef float f32x16 __attribute__((ext_vector_type(16)));
typedef float f32x4v __attribute__((ext_vector_type(4)));
typedef u32 u32x4 __attribute__((ext_vector_type(4)));
typedef u32 u32x2 __attribute__((ext_vector_type(2)));

#define BATCH    32768
#define DIN      256
#define UNITS    512
#define BM       64
#define NTHREADS 1024
#define NSTEP    6
#define DT       (1.0f/6.0f)
#define SMEM_BYTES (65536 + 65536)

__device__ __forceinline__ u16 f2bf(float f) {
  return __builtin_bit_cast(u16, (__bf16)f);
}
__device__ __forceinline__ float bf2f(u16 b) {
  return __builtin_bit_cast(float, (u32)b << 16);
}
__device__ __forceinline__ u32 pk2(float a, float b) {
  return (u32)f2bf(a) | ((u32)f2bf(b) << 16);
}
__device__ __forceinline__ float fast_tanh(float x) {
  float t = fminf(fmaxf(x * 2.885390082f, -60.f), 60.f);
  float a = __builtin_amdgcn_exp2f(t);
  return (a - 1.f) * __builtin_amdgcn_rcpf(a + 1.f);
}

// Pack K (256x512) and R (512x512) f32 row-major into bf16 B-fragment order:
// chunk c = g*512 + n holds rows g*8..g*8+7, col n (16B per lane).
__global__ void pack_weights(const float* __restrict__ Km, const float* __restrict__ Rm,
                             u16* __restrict__ Kp, u16* __restrict__ Rp) {
  int c = blockIdx.x * 256 + threadIdx.x;          // 0 .. 49151
  if (c < 32768) {
    int n = c & 511, g = c >> 9;                   // g < 64
    u32x4 p;
#pragma unroll
    for (int i = 0; i < 4; ++i) {
      u16 lo = f2bf(Rm[(g * 8 + 2 * i) * 512 + n]);
      u16 hh = f2bf(Rm[(g * 8 + 2 * i + 1) * 512 + n]);
      p[i] = (u32)lo | ((u32)hh << 16);
    }
    ((u32x4*)Rp)[c] = p;
  } else {
    int c2 = c - 32768;                            // < 16384
    int n = c2 & 511, g = c2 >> 9;                 // g < 32
    u32x4 p;
#pragma unroll
    for (int i = 0; i < 4; ++i) {
      u16 lo = f2bf(Km[(g * 8 + 2 * i) * 512 + n]);
      u16 hh = f2bf(Km[(g * 8 + 2 * i + 1) * 512 + n]);
      p[i] = (u32)lo | ((u32)hh << 16);
    }
    ((u32x4*)Kp)[c2] = p;
  }
}

__global__ __launch_bounds__(NTHREADS, 4)
void ctrnn_fused(const float* __restrict__ X, const float* __restrict__ H0,
                 const u16* __restrict__ Kp, const u16* __restrict__ Rp,
                 const float* __restrict__ bias, const float* __restrict__ scale,
                 float* __restrict__ out) {
  extern __shared__ char smem[];
  char* heL  = smem;            // 64KB: he [64 rows][512 cols] bf16, pitch 1024B, swizzled; x-stage in prologue
  char* xkbL = smem + 65536;    // 64KB: xkb bf16, fragment-linear [wv][nt][q][lane][16B]

  const int tid  = threadIdx.x;
  const int lane = tid & 63;
  const int wv   = tid >> 6;             // 0..15
  const int wm   = wv >> 3, wn = wv & 7; // 2 x 8 wave grid
  const int ln   = lane & 31, hi = lane >> 5;
  const long r0  = (long)blockIdx.x * BM;

  const int jc  = wn * 64 + ln;          // col base; +nt*32
  const int jc2 = jc * 2;
  const int mA  = wm * 32 + ln;          // A-fragment row
  const int swA = (ln & 7) << 4;
  const int mbase = wm * 32 + hi * 4;

  // stage x tile -> bf16 LDS [64][256], rows 512B pitch, swizzle ^((m&7)<<4)
  {
    const f32x4v* X4 = (const f32x4v*)(X + r0 * DIN);
#pragma unroll
    for (int i = 0; i < 4; ++i) {
      int flat = i * NTHREADS + tid;     // 0..4095 float4-chunks
      int m = flat >> 6, c4 = flat & 63;
      f32x4v v = X4[m * 64 + c4];
      u32x2 p;
      p.x = pk2(v.x, v.y);
      p.y = pk2(v.z, v.w);
      *(u32x2*)(heL + m * 512 + ((c4 * 8) ^ ((m & 7) << 4))) = p;
    }
  }

  float scl[2] = {scale[jc], scale[jc + 32]};

  __syncthreads();

  // ---- prologue: xkb = x @ K + bias (MFMA over DIN=256, 16 k-blocks) ----
  {
    f32x16 pre[2];
#pragma unroll
    for (int nt = 0; nt < 2; ++nt) {
      float b = bias[jc + nt * 32];
#pragma unroll
      for (int r = 0; r < 16; ++r) pre[nt][r] = b;
    }
    const u32x4* Kp4 = (const u32x4*)Kp;
#pragma unroll 2
    for (int kb = 0; kb < 16; ++kb) {
      bf16x8 a = __builtin_bit_cast(bf16x8,
          *(const u32x4*)(heL + mA * 512 + (((kb * 32) | (hi * 16)) ^ swA)));
      bf16x8 b0 = __builtin_bit_cast(bf16x8, Kp4[(kb * 2 + hi) * 512 + jc]);
      bf16x8 b1 = __builtin_bit_cast(bf16x8, Kp4[(kb * 2 + hi) * 512 + jc + 32]);
      pre[0] = __builtin_amdgcn_mfma_f32_32x32x16_bf16(a, b0, pre[0], 0, 0, 0);
      pre[1] = __builtin_amdgcn_mfma_f32_32x32x16_bf16(a, b1, pre[1], 0, 0, 0);
    }
    // park xkb in LDS, fragment-linear (stride-16B per lane -> conflict-free)
#pragma unroll
    for (int nt = 0; nt < 2; ++nt) {
      u32x4 p0, p1;
#pragma unroll
      for (int i = 0; i < 4; ++i) {
        p0[i] = pk2(pre[nt][2 * i],     pre[nt][2 * i + 1]);
        p1[i] = pk2(pre[nt][8 + 2 * i], pre[nt][9 + 2 * i]);
      }
      int base = ((wv * 2 + nt) * 2) * 1024 + lane * 16;
      *(u32x4*)(xkbL + base)        = p0;
      *(u32x4*)(xkbL + base + 1024) = p1;
    }
  }

  // load h (f32) in C-fragment layout
  float h[2][16];
  u32 accP[2][8];
#pragma unroll
  for (int nt = 0; nt < 2; ++nt)
#pragma unroll
    for (int r = 0; r < 16; ++r) {
      int m = mbase + (r & 3) + ((r >> 2) << 3);
      h[nt][r] = H0[(r0 + m) * UNITS + jc + nt * 32];
    }

  __syncthreads();   // all x-stage reads done; heL becomes the he buffer

  // write he_1 = bf16(h)
#pragma unroll
  for (int nt = 0; nt < 2; ++nt)
#pragma unroll
    for (int r = 0; r < 16; ++r) {
      int m = mbase + (r & 3) + ((r >> 2) << 3);
      *(u16*)(heL + m * 1024 + ((jc2 + nt * 64) ^ ((m & 7) << 4))) = f2bf(h[nt][r]);
    }
  __syncthreads();

  const u32x4* Rp4 = (const u32x4*)Rp;

  for (int step = 0; step < NSTEP; ++step) {
#pragma unroll
    for (int ev = 0; ev < 4; ++ev) {
      // pre = xkb (re-init from LDS, own-thread data)
      f32x16 pre[2];
#pragma unroll
      for (int nt = 0; nt < 2; ++nt) {
        int base = ((wv * 2 + nt) * 2) * 1024 + lane * 16;
        u32x4 q0 = *(const u32x4*)(xkbL + base);
        u32x4 q1 = *(const u32x4*)(xkbL + base + 1024);
#pragma unroll
        for (int i = 0; i < 4; ++i) {
          pre[nt][2 * i]     = bf2f((u16)(q0[i] & 0xffffu));
          pre[nt][2 * i + 1] = bf2f((u16)(q0[i] >> 16));
          pre[nt][8 + 2 * i] = bf2f((u16)(q1[i] & 0xffffu));
          pre[nt][9 + 2 * i] = bf2f((u16)(q1[i] >> 16));
        }
      }
      // pre += he @ R  (32 k-blocks; B-frags streamed from L1/L2)
#pragma unroll 2
      for (int kb = 0; kb < 32; ++kb) {
        bf16x8 a = __builtin_bit_cast(bf16x8,
            *(const u32x4*)(heL + mA * 1024 + (((kb * 32) | (hi * 16)) ^ swA)));
        bf16x8 b0 = __builtin_bit_cast(bf16x8, Rp4[(kb * 2 + hi) * 512 + jc]);
        bf16x8 b1 = __builtin_bit_cast(bf16x8, Rp4[(kb * 2 + hi) * 512 + jc + 32]);
        pre[0] = __builtin_amdgcn_mfma_f32_32x32x16_bf16(a, b0, pre[0], 0, 0, 0);
        pre[1] = __builtin_amdgcn_mfma_f32_32x32x16_bf16(a, b1, pre[1], 0, 0, 0);
      }

      // pass1: k = scale*tanh(pre) - he ; acc += wk*k ; stash k into pre regs
      const float wk = (ev == 1 || ev == 2) ? 2.f : 1.f;
      const float ce = (ev < 2) ? (DT * 0.5f) : DT;
#pragma unroll
      for (int nt = 0; nt < 2; ++nt) {
#pragma unroll
        for (int rp = 0; rp < 8; ++rp) {
          u32 ap = accP[nt][rp];
          float a0 = (ev == 0) ? 0.f : bf2f((u16)(ap & 0xffffu));
          float a1 = (ev == 0) ? 0.f : bf2f((u16)(ap >> 16));
          float kk[2];
#pragma unroll
          for (int half = 0; half < 2; ++half) {
            int r = rp * 2 + half;
            int m = mbase + (r & 3) + ((r >> 2) << 3);
            int byte = m * 1024 + ((jc2 + nt * 64) ^ ((m & 7) << 4));
            float u = scl[nt] * fast_tanh(pre[nt][r]);
            float hev = bf2f(*(const u16*)(heL + byte));
            kk[half] = u - hev;
            pre[nt][r] = kk[half];       // stash k in AGPR slot
          }
          a0 += wk * kk[0];
          a1 += wk * kk[1];
          if (ev == 3) {
            h[nt][rp * 2]     += (DT / 6.f) * a0;
            h[nt][rp * 2 + 1] += (DT / 6.f) * a1;
          } else {
            accP[nt][rp] = pk2(a0, a1);
          }
        }
      }
      __syncthreads();   // all MFMA/readback reads of heL complete

      // pass2: write he_next (ev<3: h + ce*k ; ev==3: updated h)
      if (!(step == NSTEP - 1 && ev == 3)) {
#pragma unroll
        for (int nt = 0; nt < 2; ++nt)
#pragma unroll
          for (int r = 0; r < 16; ++r) {
            int m = mbase + (r & 3) + ((r >> 2) << 3);
            int byte = m * 1024 + ((jc2 + nt * 64) ^ ((m & 7) << 4));
            float val = (ev == 3) ? h[nt][r] : h[nt][r] + ce * pre[nt][r];
            *(u16*)(heL + byte) = f2bf(val);
          }
      }
      __syncthreads();   // he_{i+1} visible
    }
  }

  // store final h
#pragma unroll
  for (int nt = 0; nt < 2; ++nt)
#pragma unroll
    for (int r = 0; r < 16; ++r) {
      int m = mbase + (r & 3) + ((r >> 2) << 3);
      out[(r0 + m) * UNITS + jc + nt * 32] = h[nt][r];
    }
}

extern "C" void kernel_launch(void* const* d_in, const int* in_sizes, int n_in,
                              void* d_out, int out_size, void* d_ws, size_t ws_size,
                              hipStream_t stream) {
  const float* X     = (const float*)d_in[0];
  const float* H0    = (const float*)d_in[1];
  const float* Km    = (const float*)d_in[2];
  const float* Rm    = (const float*)d_in[3];
  const float* bias  = (const float*)d_in[4];
  const float* scale = (const float*)d_in[5];
  float* out = (float*)d_out;

  u16* Rp = (u16*)d_ws;                  // 512*512 bf16 = 512KB
  u16* Kp = Rp + UNITS * UNITS;          // 256*512 bf16 = 256KB

  (void)hipFuncSetAttribute((const void*)ctrnn_fused,
                            hipFuncAttributeMaxDynamicSharedMemorySize, SMEM_BYTES);

  pack_weights<<<192, 256, 0, stream>>>(Km, Rm, Kp, Rp);
  ctrnn_fused<<<BATCH / BM, NTHREADS, SMEM_BYTES, stream>>>(X, H0, Kp, Rp, bias, scale, out);
}